// Round 16
// baseline (51.594 us; speedup 1.0000x reference)
//
#include <hip/hip_runtime.h>
#include <hip/hip_bf16.h>

#define B_ 16
#define C_ 64
#define N_ 16384          // 128*128
#define KCH 32            // gram chunks per batch -> 512 blocks
#define CPB 512           // columns per gram block (N_/KCH)
#define NW 128            // out: columns per block (halved -> 18KiB LDS, 8 blocks/CU)
#define SROW 72           // Xt row stride in bf16 (pad 64 -> 72)

typedef __attribute__((ext_vector_type(8))) short bf16x8;
typedef __attribute__((ext_vector_type(4))) float f32x4;
typedef __attribute__((ext_vector_type(4))) short s16x4;

// fp32 -> bf16 RNE via HW cvt (compiler fuses pairs into v_cvt_pk_bf16_f32)
__device__ __forceinline__ short f2bf(float f) {
    return (short)__bfloat16_as_ushort(__float2bfloat16(f));
}

__device__ __forceinline__ float bf2f(unsigned short u) {
    unsigned int x = ((unsigned int)u) << 16;
    return __uint_as_float(x);
}

__device__ __forceinline__ bf16x8 cvt8(float4 lo, float4 hi) {
    bf16x8 r;
    r[0] = f2bf(lo.x); r[1] = f2bf(lo.y); r[2] = f2bf(lo.z); r[3] = f2bf(lo.w);
    r[4] = f2bf(hi.x); r[5] = f2bf(hi.y); r[6] = f2bf(hi.z); r[7] = f2bf(hi.w);
    return r;
}

// -------- pass 1: per-(batch, k-chunk) partial gram via bf16 MFMA --------
// R15 exact (bf16 partials, ~4MiB roundtrip); near read floor -- leave alone.
__global__ __launch_bounds__(256)
void gram_kernel(const float* __restrict__ x, unsigned short* __restrict__ gpart) {
    __shared__ float red[2][4096];   // 32 KiB two-phase reduce buffer
    const int t = threadIdx.x, l = t & 63, w = t >> 6;
    const int b = blockIdx.y, ch = blockIdx.x;
    const float* xb = x + (size_t)b * (C_ * (size_t)N_);
    const int row = l & 15, kg = l >> 4;
    const int kbase = ch * CPB + w * (CPB / 4);

    f32x4 acc[4][4] = {};
    float4 raw[2][4][2];

    // preload k-step 0
    #pragma unroll
    for (int g = 0; g < 4; ++g) {
        const float* p = xb + (size_t)(16 * g + row) * N_ + kbase + kg * 8;
        raw[0][g][0] = *(const float4*)p;
        raw[0][g][1] = *(const float4*)(p + 4);
    }

    #pragma unroll
    for (int ks = 0; ks < 4; ++ks) {
        const int cb = ks & 1, nb = cb ^ 1;
        if (ks < 3) {   // issue next k-step's 8 loads before touching current
            #pragma unroll
            for (int g = 0; g < 4; ++g) {
                const float* p = xb + (size_t)(16 * g + row) * N_ +
                                 kbase + (ks + 1) * 32 + kg * 8;
                raw[nb][g][0] = *(const float4*)p;
                raw[nb][g][1] = *(const float4*)(p + 4);
            }
        }
        bf16x8 fr[4];
        #pragma unroll
        for (int g = 0; g < 4; ++g) fr[g] = cvt8(raw[cb][g][0], raw[cb][g][1]);
        #pragma unroll
        for (int gc = 0; gc < 4; ++gc)
            #pragma unroll
            for (int gd = 0; gd < 4; ++gd)
                acc[gc][gd] = __builtin_amdgcn_mfma_f32_16x16x32_bf16(
                    fr[gc], fr[gd], acc[gc][gd], 0, 0, 0);
    }

    // two-phase block reduce: waves 0,1 write; waves 2,3 add; all sum halves.
    if (w < 2) {
        #pragma unroll
        for (int gc = 0; gc < 4; ++gc)
            #pragma unroll
            for (int gd = 0; gd < 4; ++gd)
                *(f32x4*)&red[w][(gc * 4 + gd) * 256 + l * 4] = acc[gc][gd];
    }
    __syncthreads();
    if (w >= 2) {
        #pragma unroll
        for (int gc = 0; gc < 4; ++gc)
            #pragma unroll
            for (int gd = 0; gd < 4; ++gd) {
                float* p = &red[w - 2][(gc * 4 + gd) * 256 + l * 4];
                f32x4 v = *(f32x4*)p;
                *(f32x4*)p = v + acc[gc][gd];
            }
    }
    __syncthreads();

    // pack 8 fp32 -> bf16x8 (16B store); each thread covers elems [8t, 8t+8)
    unsigned short* dst = gpart + ((size_t)b * KCH + ch) * 4096;
    const float* r0 = red[0];
    const float* r1 = red[1];
    #pragma unroll
    for (int j = 0; j < 2; ++j) {
        const int e = j * 2048 + t * 8;
        bf16x8 pk;
        #pragma unroll
        for (int q = 0; q < 8; ++q) pk[q] = f2bf(r0[e + q] + r1[e + q]);
        *(bf16x8*)(dst + e) = pk;
    }
}

// -------- pass 2 (merged reduce+m, FULL load ILP) — R15 exact --------
__global__ __launch_bounds__(256)
void rm_kernel(const float* __restrict__ W, const unsigned short* __restrict__ gpart,
               unsigned short* __restrict__ Mbf) {
    __shared__ float Gs[C_][17];   // [c][dloc]
    __shared__ float Ws[C_][65];   // [o][c]
    const int gd = blockIdx.x, b = blockIdx.y, t = threadIdx.x;

    for (int i = t; i < C_ * C_; i += 256) Ws[i >> 6][i & 63] = W[i];

    const int f = t;  // flat in-tile index = lane*4 + reg
    #pragma unroll
    for (int gc = 0; gc < 4; ++gc) {
        const unsigned short* p = gpart + (size_t)b * KCH * 4096 + (gc * 4 + gd) * 256 + f;
        unsigned short v[KCH];
        #pragma unroll
        for (int ch = 0; ch < KCH; ++ch)           // 32 loads, all in flight
            v[ch] = p[(size_t)ch * 4096];
        float s = 0.f;
        #pragma unroll
        for (int ch = 0; ch < KCH; ch += 4)        // 4-chain tree sum
            s += ((bf2f(v[ch]) + bf2f(v[ch + 1])) + (bf2f(v[ch + 2]) + bf2f(v[ch + 3])));
        const int c = gc * 16 + (f >> 6) * 4 + (f & 3);
        const int dloc = (f >> 2) & 15;
        Gs[c][dloc] = s;
    }
    __syncthreads();

    const int o = t & 63, g2 = t >> 6;
    const float invN = 1.0f / (float)N_;
    #pragma unroll
    for (int j = 0; j < 4; ++j) {
        const int dloc = g2 * 4 + j;
        float s = 0.f;
        #pragma unroll
        for (int c = 0; c < C_; ++c) s = fmaf(Ws[o][c], Gs[c][dloc], s);
        Mbf[((size_t)b * C_ + o) * C_ + gd * 16 + dloc] = (unsigned short)f2bf(s * invN);
    }
}

// -------- pass 3: out_b = M_b @ X_b, operand-swapped, nt stores --------
// SINGLE CHANGE vs R15: n-slice 256 -> 128 (Xt 36 KiB -> 18 KiB) so out runs
// 8 blocks/CU instead of 4 (R13 diagnosis: low VALU + sub-ceiling BW =
// occupancy-bound; memset proves writes can do 6.9 TB/s with enough streams).
// launch_bounds(256,8) caps VGPR at 64 -- R13 measured exactly 64 for this body.
__global__ __launch_bounds__(256, 8)
void out_kernel(const float* __restrict__ x, const unsigned short* __restrict__ Mbf,
                float* __restrict__ out) {
    __shared__ unsigned short Xt[NW][SROW];   // 18 KiB
    const int t = threadIdx.x, l = t & 63, w = t >> 6;
    const int b = blockIdx.y, n0 = blockIdx.x * NW;
    const float* xb = x + (size_t)b * (C_ * (size_t)N_);
    const int row = l & 15, kg = l >> 4;

    // M fragments: lane l -> M[16g+row][ks*32 + kg*8 + j]  (used as B operand)
    bf16x8 mfrag[2][4];
    #pragma unroll
    for (int ks = 0; ks < 2; ++ks)
        #pragma unroll
        for (int g = 0; g < 4; ++g)
            mfrag[ks][g] = *(const bf16x8*)((const short*)Mbf +
                ((size_t)b * C_ + 16 * g + row) * C_ + ks * 32 + kg * 8);

    // stage+transpose: thread t -> d-quad d0 = (t&15)*4, col-block (t>>4)*8;
    // 4 rows x 8 cols per thread (8 float4 loads, 8 ds_write_b64).
    const int d0 = (t & 15) * 4, cb8 = (t >> 4) * 8;
    {
        float a[4][8];
        #pragma unroll
        for (int r = 0; r < 4; ++r) {
            const float* src = xb + (size_t)(d0 + r) * N_ + n0 + cb8;
            float4 q0 = *(const float4*)src;
            float4 q1 = *(const float4*)(src + 4);
            a[r][0] = q0.x; a[r][1] = q0.y; a[r][2] = q0.z; a[r][3] = q0.w;
            a[r][4] = q1.x; a[r][5] = q1.y; a[r][6] = q1.z; a[r][7] = q1.w;
        }
        #pragma unroll
        for (int j = 0; j < 8; ++j) {
            s16x4 pk;
            pk[0] = f2bf(a[0][j]); pk[1] = f2bf(a[1][j]);
            pk[2] = f2bf(a[2][j]); pk[3] = f2bf(a[3][j]);
            *(s16x4*)&Xt[cb8 + j][d0] = pk;
        }
    }
    __syncthreads();

    // wave w owns ntiles {2w, 2w+1}: 16 MFMAs, 8 dwordx4 nt stores
    float* ob = out + (size_t)b * (C_ * (size_t)N_);
    #pragma unroll
    for (int nt = 0; nt < 2; ++nt) {
        const int ntile = w * 2 + nt;
        bf16x8 xfrag0 = *(const bf16x8*)&Xt[ntile * 16 + row][kg * 8];
        bf16x8 xfrag1 = *(const bf16x8*)&Xt[ntile * 16 + row][32 + kg * 8];
        #pragma unroll
        for (int g = 0; g < 4; ++g) {
            f32x4 acc = {};
            acc = __builtin_amdgcn_mfma_f32_16x16x32_bf16(xfrag0, mfrag[0][g], acc, 0, 0, 0);
            acc = __builtin_amdgcn_mfma_f32_16x16x32_bf16(xfrag1, mfrag[1][g], acc, 0, 0, 0);
            __builtin_nontemporal_store(acc,
                (f32x4*)&ob[(size_t)(16 * g + row) * N_ + n0 + ntile * 16 + 4 * kg]);
        }
    }
}

extern "C" void kernel_launch(void* const* d_in, const int* in_sizes, int n_in,
                              void* d_out, int out_size, void* d_ws, size_t ws_size,
                              hipStream_t stream) {
    const float* x = (const float*)d_in[0];   // [16,64,128,128] fp32
    const float* w = (const float*)d_in[1];   // [64,64] fp32
    float* out = (float*)d_out;               // [16,64,128,128] fp32

    unsigned short* gpart = (unsigned short*)d_ws;                    // 4 MiB (bf16)
    unsigned short* Mbf = gpart + (size_t)B_ * KCH * 4096;            // 128 KiB

    gram_kernel<<<dim3(KCH, B_), 256, 0, stream>>>(x, gpart);
    rm_kernel<<<dim3(4, B_), 256, 0, stream>>>(w, gpart, Mbf);
    out_kernel<<<dim3(N_ / NW, B_), 256, 0, stream>>>(x, Mbf, out);
}